// Round 13
// baseline (2239.029 us; speedup 1.0000x reference)
//
#include <hip/hip_runtime.h>

#define TT 512
#define HH 256
#define BB 128

typedef unsigned long long u64;

// L2-served (L1-bypass) 8B ops: sc0 on gfx950 MUBUF/FLAT = coherent-at-L2.
__device__ __forceinline__ u64 load_l2(const u64* p) {
    u64 r;
    asm volatile("global_load_dwordx2 %0, %1, off sc0\n\ts_waitcnt vmcnt(0)"
                 : "=v"(r) : "v"(p) : "memory");
    return r;
}
__device__ __forceinline__ void store_l2(u64* p, u64 v) {
    asm volatile("global_store_dwordx2 %0, %1, off sc0" :: "v"(p), "v"(v) : "memory");
}

// 256 wgs x 1024 threads, cooperative. Group g (= wg & 31) = wgs
// {g, g+32, ..., g+224} -> all on XCD g&7 IF dispatch is round-robin.
// Batches 4g..4g+3, two phases/step (pairs {0,1} then {2,3}), R10 structure.
// Member q = wg>>5 owns h elems [32q,32q+32). Lane: kc = lane&15 (K-chunk),
// rs = lane>>4; wave w owns local rows w*8+rs*2, +1. Butterfly reduce over
// kc lanes; kc<4 stages gates to LDS; tid<64 runs cell.
//
// Exchange (NEW): dual-publish each h element -- sc0 store (producer-XCD L2,
// fast same-XCD visibility) + agent store (coherence point, guaranteed).
// Import: 3 bounded sc0 tries (~85ns each if L2-shared), then agent-scope
// poll fallback. Bounded tries + always-fresh agent path => hang-impossible.
// Epoch rides inside the 8B payload; 2-slot parity as before.
__global__ __launch_bounds__(1024)
__attribute__((amdgpu_waves_per_eu(4, 4)))
void lstm_coop(
    const float* __restrict__ x,      // [B,T]
    const float* __restrict__ W_ih,   // [1024]
    const float* __restrict__ W_hh,   // [1024,256]
    const float* __restrict__ b_ih,   // [1024]
    const float* __restrict__ b_hh,   // [1024]
    const float* __restrict__ W1,     // [128,256]
    const float* __restrict__ b1,     // [128]
    const float* __restrict__ W2,     // [128]
    const float* __restrict__ b2,     // [1]
    float* __restrict__ out,          // [B]
    u64* __restrict__ hpair)          // [2][BB][HH] {epoch,h}
{
    const int wg  = blockIdx.x;
    const int g   = wg & 31;
    const int q   = wg >> 5;
    const int tid = threadIdx.x;
    const int b0  = 4 * g;

    __shared__ float x_lds[4][TT];        // 8 KB
    __shared__ float h_lds[4][320];       // 5 KB (stride 20 per 16-chunk)
    __shared__ float gates[2][128][2];    // 2 KB
    __shared__ float cc[32][9];           // 1.1 KB
    __shared__ float red_lds[4][128];     // 2 KB

    const int w    = tid >> 6;        // wave 0..15
    const int lane = tid & 63;
    const int kc   = lane & 15;       // K-chunk
    const int rs   = lane >> 4;       // row-slot 0..3
    const int rowA = w * 8 + rs * 2;  // local rows
    const int rowB = rowA + 1;
    const int RA = (rowA >> 5) * HH + q * 32 + (rowA & 31);
    const int RB = (rowB >> 5) * HH + q * 32 + (rowB & 31);

    // resident weights: 2 rows x 16 K = 32 VGPRs
    float wa[16], wb[16];
    {
        const float4* pa = reinterpret_cast<const float4*>(W_hh + (size_t)RA * HH + 16 * kc);
        const float4* pb = reinterpret_cast<const float4*>(W_hh + (size_t)RB * HH + 16 * kc);
        #pragma unroll
        for (int k = 0; k < 4; ++k) {
            float4 va = pa[k], vb = pb[k];
            wa[4*k+0] = va.x; wa[4*k+1] = va.y; wa[4*k+2] = va.z; wa[4*k+3] = va.w;
            wb[4*k+0] = vb.x; wb[4*k+1] = vb.y; wb[4*k+2] = vb.z; wb[4*k+3] = vb.w;
        }
    }
    #pragma unroll
    for (int k = 0; k < 16; ++k) {
        asm volatile("" : "+v"(wa[k]));
        asm volatile("" : "+v"(wb[k]));
    }

    // stage x
    #pragma unroll
    for (int u = 0; u < 2; ++u) {
        int idx = tid + u * 1024;
        int m = idx >> 9, j = idx & 511;
        x_lds[m][j] = x[(size_t)(b0 + m) * TT + j];
    }
    // cell constants for element l: 4x wih + 4x bias
    if (tid < 32) {
        #pragma unroll
        for (int G = 0; G < 4; ++G) {
            const int R = G * HH + q * 32 + tid;
            cc[tid][G]     = W_ih[R];
            cc[tid][4 + G] = b_ih[R] + b_hh[R];
        }
    }

    float cA = 0.0f, cB = 0.0f;       // cell state (tid<64)
    __syncthreads();

#define PHASE(PH, CREG)                                                        \
    do {                                                                       \
        if (tid < 512) {                                                       \
            const int mm = tid >> 8, j = tid & 255;                            \
            u64* src = (u64*)&hpair[((size_t)(t & 1) * BB + (b0 + PH * 2 + mm)) * HH + j]; \
            u64 v = load_l2(src);                                              \
            int tries = 0;                                                     \
            while ((unsigned)(v >> 32) < (unsigned)t && ++tries <= 3)          \
                v = load_l2(src);                                              \
            int sp = 0;                                                        \
            while ((unsigned)(v >> 32) < (unsigned)t) {                        \
                if (sp++ > 2) __builtin_amdgcn_s_sleep(1);                     \
                v = __hip_atomic_load(src, __ATOMIC_RELAXED, __HIP_MEMORY_SCOPE_AGENT); \
            }                                                                  \
            h_lds[PH * 2 + mm][20 * (j >> 4) + (j & 15)] = __uint_as_float((unsigned)v); \
        }                                                                      \
        __syncthreads();                                                       \
        float aA0, aB0, aA1, aB1;                                              \
        dot2x16(&h_lds[PH * 2 + 0][20 * kc], wa, wb, aA0, aB0);                \
        dot2x16(&h_lds[PH * 2 + 1][20 * kc], wa, wb, aA1, aB1);                \
        aA0 += __shfl_xor(aA0, 1, 64);  aA1 += __shfl_xor(aA1, 1, 64);         \
        aB0 += __shfl_xor(aB0, 1, 64);  aB1 += __shfl_xor(aB1, 1, 64);         \
        aA0 += __shfl_xor(aA0, 2, 64);  aA1 += __shfl_xor(aA1, 2, 64);         \
        aB0 += __shfl_xor(aB0, 2, 64);  aB1 += __shfl_xor(aB1, 2, 64);         \
        aA0 += __shfl_xor(aA0, 4, 64);  aA1 += __shfl_xor(aA1, 4, 64);         \
        aB0 += __shfl_xor(aB0, 4, 64);  aB1 += __shfl_xor(aB1, 4, 64);         \
        aA0 += __shfl_xor(aA0, 8, 64);  aA1 += __shfl_xor(aA1, 8, 64);         \
        aB0 += __shfl_xor(aB0, 8, 64);  aB1 += __shfl_xor(aB1, 8, 64);         \
        if (kc < 4) {                                                          \
            const int r = (kc >> 1) ? rowB : rowA;                             \
            const float vv = (kc == 0) ? aA0 : (kc == 1) ? aA1                 \
                           : (kc == 2) ? aB0 : aB1;                            \
            gates[PH][r][kc & 1] = vv;                                         \
        }                                                                      \
        __syncthreads();                                                       \
        if (tid < 64) {                                                        \
            const int mp = tid >> 5, l = tid & 31;                             \
            const int mA = PH * 2 + mp;                                        \
            const float xv = x_lds[mA][t];                                     \
            float ig = gates[PH][     l][mp] + __builtin_fmaf(xv, cc[l][0], cc[l][4]); \
            float fg = gates[PH][32 + l][mp] + __builtin_fmaf(xv, cc[l][1], cc[l][5]); \
            float gg = gates[PH][64 + l][mp] + __builtin_fmaf(xv, cc[l][2], cc[l][6]); \
            float og = gates[PH][96 + l][mp] + __builtin_fmaf(xv, cc[l][3], cc[l][7]); \
            ig = __builtin_amdgcn_rcpf(1.f + __expf(-ig));                     \
            fg = __builtin_amdgcn_rcpf(1.f + __expf(-fg));                     \
            og = __builtin_amdgcn_rcpf(1.f + __expf(-og));                     \
            gg = 2.f * __builtin_amdgcn_rcpf(1.f + __expf(-2.f * gg)) - 1.f;   \
            CREG = __builtin_fmaf(fg, CREG, ig * gg);                          \
            float th = 2.f * __builtin_amdgcn_rcpf(1.f + __expf(-2.f * CREG)) - 1.f; \
            float hn = og * th;                                                \
            u64 pk = ((u64)(unsigned)(t + 1) << 32) | (u64)__float_as_uint(hn);\
            u64* dst = &hpair[((size_t)((t + 1) & 1) * BB + (b0 + mA)) * HH + (q * 32 + l)]; \
            store_l2(dst, pk);                                                 \
            __hip_atomic_store(dst, pk, __ATOMIC_RELAXED, __HIP_MEMORY_SCOPE_AGENT); \
        }                                                                      \
    } while (0)

    // 16 FMAs of two weight rows against one 16-wide h chunk.
#define dot2x16(hp, wa_, wb_, ra, rb)                                          \
    do {                                                                       \
        const float* h_ = (hp);                                                \
        float4 p0 = *(const float4*)(h_);                                      \
        float4 p1 = *(const float4*)(h_ + 4);                                  \
        float4 p2 = *(const float4*)(h_ + 8);                                  \
        float4 p3 = *(const float4*)(h_ + 12);                                 \
        float a_, b_;                                                          \
        a_ = wa_[0] * p0.x;                     b_ = wb_[0] * p0.x;            \
        a_ = __builtin_fmaf(wa_[1],  p0.y, a_); b_ = __builtin_fmaf(wb_[1],  p0.y, b_); \
        a_ = __builtin_fmaf(wa_[2],  p0.z, a_); b_ = __builtin_fmaf(wb_[2],  p0.z, b_); \
        a_ = __builtin_fmaf(wa_[3],  p0.w, a_); b_ = __builtin_fmaf(wb_[3],  p0.w, b_); \
        a_ = __builtin_fmaf(wa_[4],  p1.x, a_); b_ = __builtin_fmaf(wb_[4],  p1.x, b_); \
        a_ = __builtin_fmaf(wa_[5],  p1.y, a_); b_ = __builtin_fmaf(wb_[5],  p1.y, b_); \
        a_ = __builtin_fmaf(wa_[6],  p1.z, a_); b_ = __builtin_fmaf(wb_[6],  p1.z, b_); \
        a_ = __builtin_fmaf(wa_[7],  p1.w, a_); b_ = __builtin_fmaf(wb_[7],  p1.w, b_); \
        a_ = __builtin_fmaf(wa_[8],  p2.x, a_); b_ = __builtin_fmaf(wb_[8],  p2.x, b_); \
        a_ = __builtin_fmaf(wa_[9],  p2.y, a_); b_ = __builtin_fmaf(wb_[9],  p2.y, b_); \
        a_ = __builtin_fmaf(wa_[10], p2.z, a_); b_ = __builtin_fmaf(wb_[10], p2.z, b_); \
        a_ = __builtin_fmaf(wa_[11], p2.w, a_); b_ = __builtin_fmaf(wb_[11], p2.w, b_); \
        a_ = __builtin_fmaf(wa_[12], p3.x, a_); b_ = __builtin_fmaf(wb_[12], p3.x, b_); \
        a_ = __builtin_fmaf(wa_[13], p3.y, a_); b_ = __builtin_fmaf(wb_[13], p3.y, b_); \
        a_ = __builtin_fmaf(wa_[14], p3.z, a_); b_ = __builtin_fmaf(wb_[14], p3.z, b_); \
        a_ = __builtin_fmaf(wa_[15], p3.w, a_); b_ = __builtin_fmaf(wb_[15], p3.w, b_); \
        ra = a_; rb = b_;                                                      \
    } while (0)

    for (int t = 0; t < TT; ++t) {
        PHASE(0, cA);
        PHASE(1, cB);
    }
#undef PHASE
#undef dot2x16

    // ---- epilogue: q==0 imports final h (epoch TT, slot TT&1=0), runs MLP
    if (q == 0) {
        {
            const int m = tid >> 8, j = tid & 255;
            u64* src = (u64*)&hpair[((size_t)(TT & 1) * BB + (b0 + m)) * HH + j];
            u64 v = __hip_atomic_load(src, __ATOMIC_RELAXED, __HIP_MEMORY_SCOPE_AGENT);
            while ((unsigned)(v >> 32) < (unsigned)TT) {
                __builtin_amdgcn_s_sleep(1);
                v = __hip_atomic_load(src, __ATOMIC_RELAXED, __HIP_MEMORY_SCOPE_AGENT);
            }
            h_lds[m][20 * (j >> 4) + (j & 15)] = __uint_as_float((unsigned)v);
        }
        __syncthreads();
        if (tid < 512) {
            const int m = tid >> 7, j = tid & 127;
            const float4* w1p = reinterpret_cast<const float4*>(W1 + (size_t)j * HH);
            const float* hb = &h_lds[m][0];
            float s0 = 0.f, s1 = 0.f, s2 = 0.f, s3 = 0.f;
            #pragma unroll
            for (int k4 = 0; k4 < 64; ++k4) {
                float4 wv = w1p[k4];
                float4 hv = *(const float4*)(hb + 20 * (k4 >> 2) + 4 * (k4 & 3));
                s0 = __builtin_fmaf(wv.x, hv.x, s0);
                s1 = __builtin_fmaf(wv.y, hv.y, s1);
                s2 = __builtin_fmaf(wv.z, hv.z, s2);
                s3 = __builtin_fmaf(wv.w, hv.w, s3);
            }
            float rv = fmaxf((s0 + s1) + (s2 + s3) + b1[j], 0.f);
            red_lds[m][j] = rv * W2[j];
        }
        __syncthreads();
        if (tid < 4) {
            float y = b2[0];
            for (int k = 0; k < 128; ++k) y += red_lds[tid][k];
            out[b0 + tid] = y;
        }
    }
}

extern "C" void kernel_launch(void* const* d_in, const int* in_sizes, int n_in,
                              void* d_out, int out_size, void* d_ws, size_t ws_size,
                              hipStream_t stream) {
    const float* x    = (const float*)d_in[0];
    const float* W_ih = (const float*)d_in[1];
    const float* W_hh = (const float*)d_in[2];
    const float* b_ih = (const float*)d_in[3];
    const float* b_hh = (const float*)d_in[4];
    const float* W1   = (const float*)d_in[5];
    const float* b1   = (const float*)d_in[6];
    const float* W2   = (const float*)d_in[7];
    const float* b2   = (const float*)d_in[8];
    float* out  = (float*)d_out;

    u64* hpair = (u64*)d_ws;                    // [2][128][256] x 8B = 512 KB

    // epochs must be 0 at every call (d_ws persists across graph replays)
    (void)hipMemsetAsync(d_ws, 0, (size_t)2 * BB * HH * sizeof(u64), stream);

    void* args[] = {(void*)&x, (void*)&W_ih, (void*)&W_hh, (void*)&b_ih, (void*)&b_hh,
                    (void*)&W1, (void*)&b1, (void*)&W2, (void*)&b2,
                    (void*)&out, (void*)&hpair};
    (void)hipLaunchCooperativeKernel((void*)lstm_coop, dim3(256), dim3(1024), args, 0, stream);
}

// Round 14
// 1954.712 us; speedup vs baseline: 1.1455x; 1.1455x over previous
//
#include <hip/hip_runtime.h>

#define TT 512
#define HH 256
#define BB 128

typedef unsigned long long u64;

// 16 FMAs of two weight rows against one 16-wide h chunk.
__device__ __forceinline__ void dot2(const float* h, const float* wa_,
                                     const float* wb_, float& ra, float& rb) {
    float4 p0 = *(const float4*)(h);
    float4 p1 = *(const float4*)(h + 4);
    float a, b;
    a = wa_[0] * p0.x;                    b = wb_[0] * p0.x;
    a = __builtin_fmaf(wa_[1], p0.y, a);  b = __builtin_fmaf(wb_[1], p0.y, b);
    a = __builtin_fmaf(wa_[2], p0.z, a);  b = __builtin_fmaf(wb_[2], p0.z, b);
    a = __builtin_fmaf(wa_[3], p0.w, a);  b = __builtin_fmaf(wb_[3], p0.w, b);
    a = __builtin_fmaf(wa_[4], p1.x, a);  b = __builtin_fmaf(wb_[4], p1.x, b);
    a = __builtin_fmaf(wa_[5], p1.y, a);  b = __builtin_fmaf(wb_[5], p1.y, b);
    a = __builtin_fmaf(wa_[6], p1.z, a);  b = __builtin_fmaf(wb_[6], p1.z, b);
    a = __builtin_fmaf(wa_[7], p1.w, a);  b = __builtin_fmaf(wb_[7], p1.w, b);
    float4 p2 = *(const float4*)(h + 8);
    float4 p3 = *(const float4*)(h + 12);
    a = __builtin_fmaf(wa_[8],  p2.x, a); b = __builtin_fmaf(wb_[8],  p2.x, b);
    a = __builtin_fmaf(wa_[9],  p2.y, a); b = __builtin_fmaf(wb_[9],  p2.y, b);
    a = __builtin_fmaf(wa_[10], p2.z, a); b = __builtin_fmaf(wb_[10], p2.z, b);
    a = __builtin_fmaf(wa_[11], p2.w, a); b = __builtin_fmaf(wb_[11], p2.w, b);
    a = __builtin_fmaf(wa_[12], p3.x, a); b = __builtin_fmaf(wb_[12], p3.x, b);
    a = __builtin_fmaf(wa_[13], p3.y, a); b = __builtin_fmaf(wb_[13], p3.y, b);
    a = __builtin_fmaf(wa_[14], p3.z, a); b = __builtin_fmaf(wb_[14], p3.z, b);
    a = __builtin_fmaf(wa_[15], p3.w, a); b = __builtin_fmaf(wb_[15], p3.w, b);
    ra = a; rb = b;
}

// 256 wgs x 1024 threads, cooperative. Group g (= wg & 31) = wgs
// {g, g+32, ..., g+224}, batches 4g..4g+3, two phases/step (pairs {0,1},
// {2,3}). Member q = wg>>5 owns h elems [32q,32q+32).
// Import/publish/exchange: byte-identical to R10 (epoch-tagged {epoch,h}
// 8B agent-scope relaxed atomics, 2-slot parity).
// NEW lane layout: lane = rs + 4*kc; rs = GATE 0..3, kc = K-chunk 0..15.
// Wave w owns elems {2w, 2w+1} of both pair batches (4 cells, lanes 0-3).
// Butterfly over kc (xor 4,8,16,32) reduces each acc; 4-round broadcast
// hands lanes 0-3 all four gates of their cell -> cell + publish fully
// in-wave: ONE barrier per phase, no gates LDS, cell parallel on 16 waves.
__global__ __launch_bounds__(1024)
__attribute__((amdgpu_waves_per_eu(4, 4)))
void lstm_coop(
    const float* __restrict__ x,      // [B,T]
    const float* __restrict__ W_ih,   // [1024]
    const float* __restrict__ W_hh,   // [1024,256]
    const float* __restrict__ b_ih,   // [1024]
    const float* __restrict__ b_hh,   // [1024]
    const float* __restrict__ W1,     // [128,256]
    const float* __restrict__ b1,     // [128]
    const float* __restrict__ W2,     // [128]
    const float* __restrict__ b2,     // [1]
    float* __restrict__ out,          // [B]
    u64* __restrict__ hpair)          // [2][BB][HH] {epoch,h}
{
    const int wg  = blockIdx.x;
    const int g   = wg & 31;
    const int q   = wg >> 5;
    const int tid = threadIdx.x;
    const int b0  = 4 * g;

    __shared__ float x_lds[4][TT];        // 8 KB
    __shared__ float h_lds[4][320];       // 5 KB (stride 20 per 16-chunk)
    __shared__ float cc[32][8];           // 1 KB (4x wih + 4x bias per elem)
    __shared__ float red_lds[4][128];     // 2 KB

    const int w    = tid >> 6;        // wave 0..15 -> elems 2w, 2w+1
    const int lane = tid & 63;
    const int rs   = lane & 3;        // gate index 0..3
    const int kc   = lane >> 2;       // K-chunk 0..15
    const int eA   = 2 * w;           // local elems
    const int eB   = 2 * w + 1;
    const int RA = rs * HH + q * 32 + eA;   // gate rs, elem eA
    const int RB = rs * HH + q * 32 + eB;   // gate rs, elem eB

    // resident weights: 2 rows x 16 K = 32 VGPRs
    float wa[16], wb[16];
    {
        const float4* pa = reinterpret_cast<const float4*>(W_hh + (size_t)RA * HH + 16 * kc);
        const float4* pb = reinterpret_cast<const float4*>(W_hh + (size_t)RB * HH + 16 * kc);
        #pragma unroll
        for (int k = 0; k < 4; ++k) {
            float4 va = pa[k], vb = pb[k];
            wa[4*k+0] = va.x; wa[4*k+1] = va.y; wa[4*k+2] = va.z; wa[4*k+3] = va.w;
            wb[4*k+0] = vb.x; wb[4*k+1] = vb.y; wb[4*k+2] = vb.z; wb[4*k+3] = vb.w;
        }
    }
    #pragma unroll
    for (int k = 0; k < 16; ++k) {
        asm volatile("" : "+v"(wa[k]));
        asm volatile("" : "+v"(wb[k]));
    }

    // stage x for 4 batches
    #pragma unroll
    for (int u = 0; u < 2; ++u) {
        int idx = tid + u * 1024;
        int m = idx >> 9, j = idx & 511;
        x_lds[m][j] = x[(size_t)(b0 + m) * TT + j];
    }
    // cell constants per elem l: 4x wih + 4x bias
    if (tid < 32) {
        #pragma unroll
        for (int G = 0; G < 4; ++G) {
            const int R = G * HH + q * 32 + tid;
            cc[tid][G]     = W_ih[R];
            cc[tid][4 + G] = b_ih[R] + b_hh[R];
        }
    }

    // per-lane cell state (lanes 0-3 of each wave), one per phase
    float c0 = 0.f, c1 = 0.f;
    __syncthreads();

// PHASE P (pair batches {2P, 2P+1}): import epoch t -> h_lds (R10-identical);
// barrier; dot 4 accs; butterfly over kc; 4-round gate broadcast; in-wave
// cell + publish on lanes 0-3.
#define PHASE(P, CREG)                                                          \
    do {                                                                        \
        if (tid < 512) {                                                        \
            const int mm = tid >> 8, j = tid & 255;                             \
            const u64* sp_ = &hpair[((size_t)(t & 1) * BB + (b0 + 2 * P + mm)) * HH + j]; \
            u64 v_ = __hip_atomic_load(sp_, __ATOMIC_RELAXED, __HIP_MEMORY_SCOPE_AGENT); \
            int sp = 0;                                                         \
            while ((unsigned)(v_ >> 32) < (unsigned)t) {                        \
                if (sp++ > 2) __builtin_amdgcn_s_sleep(1);                      \
                v_ = __hip_atomic_load(sp_, __ATOMIC_RELAXED, __HIP_MEMORY_SCOPE_AGENT); \
            }                                                                   \
            h_lds[2 * P + mm][20 * (j >> 4) + (j & 15)] = __uint_as_float((unsigned)v_); \
        }                                                                       \
        __syncthreads();                                                        \
        /* acc0=(eA,m0) acc1=(eA,m1) acc2=(eB,m0) acc3=(eB,m1) */               \
        float a0_, a1_, a2_, a3_;                                               \
        dot2(&h_lds[2 * P + 0][20 * kc], wa, wb, a0_, a2_);                     \
        dot2(&h_lds[2 * P + 1][20 * kc], wa, wb, a1_, a3_);                     \
        a0_ += __shfl_xor(a0_, 4, 64);  a1_ += __shfl_xor(a1_, 4, 64);          \
        a2_ += __shfl_xor(a2_, 4, 64);  a3_ += __shfl_xor(a3_, 4, 64);          \
        a0_ += __shfl_xor(a0_, 8, 64);  a1_ += __shfl_xor(a1_, 8, 64);          \
        a2_ += __shfl_xor(a2_, 8, 64);  a3_ += __shfl_xor(a3_, 8, 64);          \
        a0_ += __shfl_xor(a0_, 16, 64); a1_ += __shfl_xor(a1_, 16, 64);         \
        a2_ += __shfl_xor(a2_, 16, 64); a3_ += __shfl_xor(a3_, 16, 64);         \
        a0_ += __shfl_xor(a0_, 32, 64); a1_ += __shfl_xor(a1_, 32, 64);         \
        a2_ += __shfl_xor(a2_, 32, 64); a3_ += __shfl_xor(a3_, 32, 64);         \
        /* 4-round broadcast: round c serves lane c (cell c) */                 \
        float gi = 0.f, gf = 0.f, gg_ = 0.f, go = 0.f;                          \
        {                                                                       \
            float t0 = __shfl(a0_, 0, 64), t1 = __shfl(a0_, 1, 64);             \
            float t2 = __shfl(a0_, 2, 64), t3 = __shfl(a0_, 3, 64);             \
            if (lane == 0) { gi = t0; gf = t1; gg_ = t2; go = t3; }             \
        }                                                                       \
        {                                                                       \
            float t0 = __shfl(a1_, 0, 64), t1 = __shfl(a1_, 1, 64);             \
            float t2 = __shfl(a1_, 2, 64), t3 = __shfl(a1_, 3, 64);             \
            if (lane == 1) { gi = t0; gf = t1; gg_ = t2; go = t3; }             \
        }                                                                       \
        {                                                                       \
            float t0 = __shfl(a2_, 0, 64), t1 = __shfl(a2_, 1, 64);             \
            float t2 = __shfl(a2_, 2, 64), t3 = __shfl(a2_, 3, 64);             \
            if (lane == 2) { gi = t0; gf = t1; gg_ = t2; go = t3; }             \
        }                                                                       \
        {                                                                       \
            float t0 = __shfl(a3_, 0, 64), t1 = __shfl(a3_, 1, 64);             \
            float t2 = __shfl(a3_, 2, 64), t3 = __shfl(a3_, 3, 64);             \
            if (lane == 3) { gi = t0; gf = t1; gg_ = t2; go = t3; }             \
        }                                                                       \
        if (lane < 4) {                                                         \
            const int me = 2 * w + (lane >> 1);      /* local elem */           \
            const int mb = lane & 1;                 /* batch in pair */        \
            const int mA = 2 * P + mb;                                          \
            const float xv = x_lds[mA][t];                                      \
            gi  += __builtin_fmaf(xv, cc[me][0], cc[me][4]);                    \
            gf  += __builtin_fmaf(xv, cc[me][1], cc[me][5]);                    \
            gg_ += __builtin_fmaf(xv, cc[me][2], cc[me][6]);                    \
            go  += __builtin_fmaf(xv, cc[me][3], cc[me][7]);                    \
            gi  = __builtin_amdgcn_rcpf(1.f + __expf(-gi));                     \
            gf  = __builtin_amdgcn_rcpf(1.f + __expf(-gf));                     \
            go  = __builtin_amdgcn_rcpf(1.f + __expf(-go));                     \
            gg_ = 2.f * __builtin_amdgcn_rcpf(1.f + __expf(-2.f * gg_)) - 1.f;  \
            float cval = __builtin_fmaf(gf, CREG, gi * gg_);                    \
            CREG = cval;                                                        \
            float th = 2.f * __builtin_amdgcn_rcpf(1.f + __expf(-2.f * cval)) - 1.f; \
            float hn = go * th;                                                 \
            u64 pk = ((u64)(unsigned)(t + 1) << 32) | (u64)__float_as_uint(hn); \
            __hip_atomic_store(&hpair[((size_t)((t + 1) & 1) * BB + (b0 + mA)) * HH + (q * 32 + me)], \
                               pk, __ATOMIC_RELAXED, __HIP_MEMORY_SCOPE_AGENT); \
        }                                                                       \
    } while (0)

    for (int t = 0; t < TT; ++t) {
        PHASE(0, c0);
        PHASE(1, c1);
    }
#undef PHASE

    // NOTE on cell-state mapping: cell c=lane uses a fixed (elem, batch) all
    // steps; CREG per (phase, lane) is consistent across iterations.

    // ---- epilogue: q==0 imports final h (epoch TT, slot TT&1=0) and runs MLP
    if (q == 0) {
        {
            const int m = tid >> 8, j = tid & 255;
            const u64* src = &hpair[((size_t)(TT & 1) * BB + (b0 + m)) * HH + j];
            u64 v = __hip_atomic_load(src, __ATOMIC_RELAXED, __HIP_MEMORY_SCOPE_AGENT);
            while ((unsigned)(v >> 32) < (unsigned)TT) {
                __builtin_amdgcn_s_sleep(1);
                v = __hip_atomic_load(src, __ATOMIC_RELAXED, __HIP_MEMORY_SCOPE_AGENT);
            }
            h_lds[m][20 * (j >> 4) + (j & 15)] = __uint_as_float((unsigned)v);
        }
        __syncthreads();
        if (tid < 512) {
            const int m = tid >> 7, j = tid & 127;
            const float4* w1p = reinterpret_cast<const float4*>(W1 + (size_t)j * HH);
            const float* hb = &h_lds[m][0];
            float s0 = 0.f, s1 = 0.f, s2 = 0.f, s3 = 0.f;
            #pragma unroll
            for (int k4 = 0; k4 < 64; ++k4) {
                float4 wv = w1p[k4];
                float4 hv = *(const float4*)(hb + 20 * (k4 >> 2) + 4 * (k4 & 3));
                s0 = __builtin_fmaf(wv.x, hv.x, s0);
                s1 = __builtin_fmaf(wv.y, hv.y, s1);
                s2 = __builtin_fmaf(wv.z, hv.z, s2);
                s3 = __builtin_fmaf(wv.w, hv.w, s3);
            }
            float rv = fmaxf((s0 + s1) + (s2 + s3) + b1[j], 0.f);
            red_lds[m][j] = rv * W2[j];
        }
        __syncthreads();
        if (tid < 4) {
            float y = b2[0];
            for (int k = 0; k < 128; ++k) y += red_lds[tid][k];
            out[b0 + tid] = y;
        }
    }
}

extern "C" void kernel_launch(void* const* d_in, const int* in_sizes, int n_in,
                              void* d_out, int out_size, void* d_ws, size_t ws_size,
                              hipStream_t stream) {
    const float* x    = (const float*)d_in[0];
    const float* W_ih = (const float*)d_in[1];
    const float* W_hh = (const float*)d_in[2];
    const float* b_ih = (const float*)d_in[3];
    const float* b_hh = (const float*)d_in[4];
    const float* W1   = (const float*)d_in[5];
    const float* b1   = (const float*)d_in[6];
    const float* W2   = (const float*)d_in[7];
    const float* b2   = (const float*)d_in[8];
    float* out  = (float*)d_out;

    u64* hpair = (u64*)d_ws;                    // [2][128][256] x 8B = 512 KB

    // epochs must be 0 at every call (d_ws persists across graph replays)
    (void)hipMemsetAsync(d_ws, 0, (size_t)2 * BB * HH * sizeof(u64), stream);

    void* args[] = {(void*)&x, (void*)&W_ih, (void*)&W_hh, (void*)&b_ih, (void*)&b_hh,
                    (void*)&W1, (void*)&b1, (void*)&W2, (void*)&b2,
                    (void*)&out, (void*)&hpair};
    (void)hipLaunchCooperativeKernel((void*)lstm_coop, dim3(256), dim3(1024), args, 0, stream);
}

// Round 15
// 988.761 us; speedup vs baseline: 2.2645x; 1.9769x over previous
//
#include <hip/hip_runtime.h>

#define TT 512
#define HH 256

typedef _Float16 half2t __attribute__((ext_vector_type(2)));

// fp16-pair dot with fp32 accumulate (v_dot2_f32_f16 when available).
__device__ __forceinline__ float dot2acc(unsigned w, unsigned h, float acc) {
#if __has_builtin(__builtin_amdgcn_fdot2)
    return __builtin_amdgcn_fdot2(__builtin_bit_cast(half2t, w),
                                  __builtin_bit_cast(half2t, h), acc, false);
#else
    union U { unsigned u; _Float16 f[2]; };
    U uw, uh; uw.u = w; uh.u = h;
    acc = __builtin_fmaf((float)uw.f[0], (float)uh.f[0], acc);
    acc = __builtin_fmaf((float)uw.f[1], (float)uh.f[1], acc);
    return acc;
#endif
}

__device__ __forceinline__ unsigned packh2(float a, float b) {
    union U { _Float16 f[2]; unsigned u; } r;
    r.f[0] = (_Float16)a; r.f[1] = (_Float16)b;   // RNE conversion
    return r.u;
}

// C=1: one 512-thread wg per batch (128 wgs, plain launch). NO cross-CU
// exchange: the entire recurrence lives in one CU. W_hh as fp16 pairs:
// thread j owns gate-rows j (gates i/f) and j+512 (gates g/o);
// K[0..191] in 192 packed VGPRs, K[192..255] in 128KB LDS (lane-consecutive
// uint4 blocks, conflict-free). h as 128 fp16-pairs in LDS (broadcast reads).
// Each thread's acc = complete row sum -> no reduction; 2 barriers/step.
// __launch_bounds__(512,1) + 136KB LDS => 1 wg/CU, 2 waves/SIMD, VGPR
// budget 256 (the untested knob; rounds 2-4 only tried waves_per_eu@1024thr).
__global__ __launch_bounds__(512, 1) void lstm_single(
    const float* __restrict__ x,      // [B,T]
    const float* __restrict__ W_ih,   // [1024]
    const float* __restrict__ W_hh,   // [1024,256]
    const float* __restrict__ b_ih,   // [1024]
    const float* __restrict__ b_hh,   // [1024]
    const float* __restrict__ W1,     // [128,256]
    const float* __restrict__ b1,     // [128]
    const float* __restrict__ W2,     // [128]
    const float* __restrict__ b2,     // [1]
    float* __restrict__ out)          // [B]
{
    const int b = blockIdx.x;
    const int j = threadIdx.x;        // 0..511

    __shared__ unsigned wl[16][512][4];   // 128 KB: LDS weight tail (uint4/thread/blk)
    __shared__ unsigned h_lds[128];       // 512 B: h as fp16 pairs
    __shared__ float    h32[HH];          // 1 KB: h fp32 (epilogue)
    __shared__ float    gates[1024];      // 4 KB
    __shared__ float    x_lds[TT];        // 2 KB
    __shared__ float    red[128];         // 512 B

    const int rA = j;                 // gate-rows: rA in {i,f}, rB in {g,o}
    const int rB = j + 512;
    const float* pA = W_hh + (size_t)rA * HH;
    const float* pB = W_hh + (size_t)rB * HH;

    // ---- stage weights: K[0..191] -> 192 packed VGPRs, K[192..255] -> LDS
    unsigned wvA[96], wvB[96];
    #pragma unroll
    for (int k = 0; k < 96; ++k) {
        wvA[k] = packh2(pA[2 * k], pA[2 * k + 1]);
        wvB[k] = packh2(pB[2 * k], pB[2 * k + 1]);
    }
    #pragma unroll
    for (int k = 0; k < 96; ++k) {
        asm volatile("" : "+v"(wvA[k]));
        asm volatile("" : "+v"(wvB[k]));
    }
    #pragma unroll
    for (int blk = 0; blk < 8; ++blk) {
        #pragma unroll
        for (int u = 0; u < 4; ++u) {
            const int k = 192 + 2 * (blk * 4 + u);   // fp32 element index
            wl[blk][j][u]     = packh2(pA[k], pA[k + 1]);
            wl[8 + blk][j][u] = packh2(pB[k], pB[k + 1]);
        }
    }

    // per-row input weight + bias
    const float wihA  = W_ih[rA];
    const float biasA = b_ih[rA] + b_hh[rA];
    const float wihB  = W_ih[rB];
    const float biasB = b_ih[rB] + b_hh[rB];

    // stage x; init h
    x_lds[j] = x[(size_t)b * TT + j];
    if (j < 128) h_lds[j] = 0u;
    if (j < 256) h32[j] = 0.0f;
    float c = 0.0f;                   // cell state (threads 0..255, elem j)
    __syncthreads();

    for (int t = 0; t < TT; ++t) {
        // ---- dot: both rows vs full h (fp16 pairs), fp32 accumulate
        float accA = 0.f, accB = 0.f;
        const uint4* hq4 = reinterpret_cast<const uint4*>(h_lds);
        #pragma unroll
        for (int i = 0; i < 24; ++i) {                 // words 0..95 (VGPR weights)
            uint4 hq = hq4[i];                         // broadcast ds_read_b128
            accA = dot2acc(wvA[4*i+0], hq.x, accA); accB = dot2acc(wvB[4*i+0], hq.x, accB);
            accA = dot2acc(wvA[4*i+1], hq.y, accA); accB = dot2acc(wvB[4*i+1], hq.y, accB);
            accA = dot2acc(wvA[4*i+2], hq.z, accA); accB = dot2acc(wvB[4*i+2], hq.z, accB);
            accA = dot2acc(wvA[4*i+3], hq.w, accA); accB = dot2acc(wvB[4*i+3], hq.w, accB);
        }
        #pragma unroll
        for (int blk = 0; blk < 8; ++blk) {            // words 96..127 (LDS weights)
            uint4 hq  = hq4[24 + blk];
            uint4 wqA = *reinterpret_cast<const uint4*>(&wl[blk][j][0]);
            uint4 wqB = *reinterpret_cast<const uint4*>(&wl[8 + blk][j][0]);
            accA = dot2acc(wqA.x, hq.x, accA); accB = dot2acc(wqB.x, hq.x, accB);
            accA = dot2acc(wqA.y, hq.y, accA); accB = dot2acc(wqB.y, hq.y, accB);
            accA = dot2acc(wqA.z, hq.z, accA); accB = dot2acc(wqB.z, hq.z, accB);
            accA = dot2acc(wqA.w, hq.w, accA); accB = dot2acc(wqB.w, hq.w, accB);
        }
        const float xv = x_lds[t];
        gates[j]       = accA + __builtin_fmaf(xv, wihA, biasA);
        gates[j + 512] = accB + __builtin_fmaf(xv, wihB, biasB);
        __syncthreads();

        // ---- cell update: threads 0..255 (element j)
        if (j < 256) {
            float gi = gates[j];
            float gf = gates[256 + j];
            float gg = gates[512 + j];
            float go = gates[768 + j];
            gi = __builtin_amdgcn_rcpf(1.f + __expf(-gi));
            gf = __builtin_amdgcn_rcpf(1.f + __expf(-gf));
            go = __builtin_amdgcn_rcpf(1.f + __expf(-go));
            gg = 2.f * __builtin_amdgcn_rcpf(1.f + __expf(-2.f * gg)) - 1.f;
            c = __builtin_fmaf(gf, c, gi * gg);
            float th = 2.f * __builtin_amdgcn_rcpf(1.f + __expf(-2.f * c)) - 1.f;
            float hn = go * th;
            h32[j] = hn;
            reinterpret_cast<unsigned short*>(h_lds)[j] =
                __builtin_bit_cast(unsigned short, (_Float16)hn);
        }
        __syncthreads();
    }

    // ---- epilogue MLP: y = relu(h @ W1.T + b1) @ W2.T + b2
    if (j < 128) {
        const float4* w1p = reinterpret_cast<const float4*>(W1 + (size_t)j * HH);
        const float4* hp  = reinterpret_cast<const float4*>(h32);
        float s0 = 0.f, s1 = 0.f, s2 = 0.f, s3 = 0.f;
        #pragma unroll
        for (int k = 0; k < 64; ++k) {
            float4 wv = w1p[k], hv = hp[k];
            s0 = __builtin_fmaf(wv.x, hv.x, s0);
            s1 = __builtin_fmaf(wv.y, hv.y, s1);
            s2 = __builtin_fmaf(wv.z, hv.z, s2);
            s3 = __builtin_fmaf(wv.w, hv.w, s3);
        }
        float rv = fmaxf((s0 + s1) + (s2 + s3) + b1[j], 0.f);
        red[j] = rv * W2[j];
    }
    __syncthreads();
    if (j == 0) {
        float y = b2[0];
        #pragma unroll 4
        for (int k = 0; k < 128; ++k) y += red[k];
        out[b] = y;
    }
}

extern "C" void kernel_launch(void* const* d_in, const int* in_sizes, int n_in,
                              void* d_out, int out_size, void* d_ws, size_t ws_size,
                              hipStream_t stream) {
    const float* x    = (const float*)d_in[0];
    const float* W_ih = (const float*)d_in[1];
    const float* W_hh = (const float*)d_in[2];
    const float* b_ih = (const float*)d_in[3];
    const float* b_hh = (const float*)d_in[4];
    const float* W1   = (const float*)d_in[5];
    const float* b1   = (const float*)d_in[6];
    const float* W2   = (const float*)d_in[7];
    const float* b2   = (const float*)d_in[8];
    float* out = (float*)d_out;

    lstm_single<<<128, 512, 0, stream>>>(x, W_ih, W_hh, b_ih, b_hh,
                                         W1, b1, W2, b2, out);
}